// Round 13
// baseline (154.367 us; speedup 1.0000x reference)
//
#include <hip/hip_runtime.h>
#include <math.h>

// B=4096, N=200, D=128, V=100000
//   h = gelu(x @ W_mu + b_mu);  logits[b,n] = dot(h[b], emb[cand[b,n]]) + mu_bias[cand[b,n]]
//
// History:
//  R4  (2 dispatch, direct gather): wall 157.5us; gather kernel 64us, 200MB @3.3TB/s.
//  R5  (9 dispatch, vocab-binned):  wall 246us — FETCH 49MB but latency-shape + overhead.
//  R8  (1 coop dispatch):           wall 970us — grid.sync() kills XCD L2 residency.
//  R12 (1 dispatch, 2 rows/block):  wall 153.7us; kernel 75us = 64us gather + 11us GEMV
//       (2048 blocks x 64KB W re-read = 128MB L2 traffic + barrier).
//  Overhead model (confirmed 3x): wall ~= 65us + 11us/dispatch + sum(kernels).
//  R13: 1024-thread blocks, 8 rows/block, 512 blocks -> W redundancy 128->32MB.
//       Gather phase per-wave identical to R4 (the measured 3.3TB/s shape).

#define BDIM 4096
#define NCAND 200
#define DDIM 128

__global__ __launch_bounds__(1024) void fused_head_dot(
    const float* __restrict__ x, const int* __restrict__ cand,
    const float* __restrict__ W, const float* __restrict__ bvec,
    const float* __restrict__ bias, const float* __restrict__ emb,
    float* __restrict__ out) {
  __shared__ float xs[8][DDIM];
  __shared__ float hs[8][DDIM];
  const int t = threadIdx.x;
  const int b0 = blockIdx.x * 8; // eight batch rows per block

  // ---- phase 1: h[b0..b0+7] = gelu(x @ W + b) ----
  // stage 8 x-rows (1024 floats = 256 float4)
  if (t < 256) {
    reinterpret_cast<float4*>(&xs[0][0])[t] =
        reinterpret_cast<const float4*>(x + (size_t)b0 * DDIM)[t];
  }
  __syncthreads();
  {
    const int col = t & 127;
    const int rr = t >> 7; // 0..7, wave-uniform
    float acc = 0.f;
#pragma unroll 8
    for (int k = 0; k < DDIM; ++k)
      acc = fmaf(xs[rr][k], W[k * DDIM + col], acc); // W coalesced, L2-hot
    acc += bvec[col];
    hs[rr][col] = 0.5f * acc * (1.0f + erff(acc * 0.70710678118654752f));
  }
  __syncthreads();

  // ---- phase 2: gather-dot (R4-proven per-wave shape) ----
  // wave wv (0..15): row r = wv>>1, half = wv&1 (candidates [100*half, +100))
  const int wv = t >> 6;
  const int lane = t & 63;
  const int l16 = lane & 15;
  const int grp = lane >> 4;
  const int r = wv >> 1;
  const int half = wv & 1;
  const int b = b0 + r;

  const float4 h1 = reinterpret_cast<const float4*>(&hs[r][0])[l16];
  const float4 h2 = reinterpret_cast<const float4*>(&hs[r][0])[l16 + 16];

  const int nstart = half * 100;
  const int nend = nstart + 100;
  const int rowbase = b * NCAND;

  for (int n0 = nstart; n0 < nend; n0 += 64) {
    const int nseg = min(64, nend - n0); // 64 then 36 (both %4==0)
    int ci = 0;
    float bv = 0.f;
    if (lane < nseg) {
      ci = cand[rowbase + n0 + lane];
      bv = bias[ci]; // 400KB table, L2/L3-resident
    }
    const int iters = nseg >> 2;
#pragma unroll 4
    for (int i = 0; i < iters; ++i) {
      const int slot = i * 4 + grp;
      const int c = __shfl(ci, slot);
      const float4* ev = reinterpret_cast<const float4*>(emb + (size_t)c * DDIM);
      const float4 v1 = ev[l16];
      const float4 v2 = ev[l16 + 16];
      float acc = v1.x * h1.x;
      acc = fmaf(v1.y, h1.y, acc);
      acc = fmaf(v1.z, h1.z, acc);
      acc = fmaf(v1.w, h1.w, acc);
      acc = fmaf(v2.x, h2.x, acc);
      acc = fmaf(v2.y, h2.y, acc);
      acc = fmaf(v2.z, h2.z, acc);
      acc = fmaf(v2.w, h2.w, acc);
      // 16-lane butterfly (shared across the 4 groups)
      acc += __shfl_xor(acc, 1);
      acc += __shfl_xor(acc, 2);
      acc += __shfl_xor(acc, 4);
      acc += __shfl_xor(acc, 8);
      const float bslot = __shfl(bv, slot);
      if (l16 == 0) out[rowbase + n0 + slot] = acc + bslot;
    }
  }
}

extern "C" void kernel_launch(void* const* d_in, const int* in_sizes, int n_in,
                              void* d_out, int out_size, void* d_ws, size_t ws_size,
                              hipStream_t stream) {
  const float* x = (const float*)d_in[0];
  const int* candidates = (const int*)d_in[1];
  const float* W_mu = (const float*)d_in[2];
  const float* b_mu = (const float*)d_in[3];
  const float* mu_bias = (const float*)d_in[4];
  const float* emb_table = (const float*)d_in[5];
  float* out = (float*)d_out;

  fused_head_dot<<<BDIM / 8, 1024, 0, stream>>>(x, candidates, W_mu, b_mu,
                                                mu_bias, emb_table, out);
}